// Round 1
// baseline (396.957 us; speedup 1.0000x reference)
//
#include <hip/hip_runtime.h>
#include <hip/hip_bf16.h>

#define M_TOK 8192
#define IN_F  1024
#define OUT_F 1024
#define N_EXP 8

typedef __attribute__((ext_vector_type(8))) _Float16 f16x8;
typedef __attribute__((ext_vector_type(4))) _Float16 f16x4;
typedef __attribute__((ext_vector_type(4))) float    f32x4;

// ---------------- gate: g = softmax(x @ Wg + bg), fp32 ----------------
__global__ void moe_gate_kernel(const float* __restrict__ x, const float* __restrict__ Wg,
                                const float* __restrict__ bg, float* __restrict__ g) {
    int token = blockIdx.x * 4 + (threadIdx.x >> 6);
    int lane  = threadIdx.x & 63;
    const float* xr = x + (size_t)token * IN_F;
    float acc[8] = {0.f,0.f,0.f,0.f,0.f,0.f,0.f,0.f};
    for (int i = lane; i < IN_F; i += 64) {
        float xv = xr[i];
        const float* wr = Wg + i * 8;
#pragma unroll
        for (int e = 0; e < 8; ++e) acc[e] = fmaf(xv, wr[e], acc[e]);
    }
#pragma unroll
    for (int e = 0; e < 8; ++e) {
        float v = acc[e];
#pragma unroll
        for (int off = 32; off > 0; off >>= 1) v += __shfl_xor(v, off, 64);
        acc[e] = v + bg[e];
    }
    float mx = acc[0];
#pragma unroll
    for (int e = 1; e < 8; ++e) mx = fmaxf(mx, acc[e]);
    float sum = 0.f;
#pragma unroll
    for (int e = 0; e < 8; ++e) { acc[e] = __expf(acc[e] - mx); sum += acc[e]; }
    float inv = 1.0f / sum;
    if (lane == 0) {
        float4 p0 = {acc[0]*inv, acc[1]*inv, acc[2]*inv, acc[3]*inv};
        float4 p1 = {acc[4]*inv, acc[5]*inv, acc[6]*inv, acc[7]*inv};
        float4* gp = (float4*)(g + (size_t)token * 8);
        gp[0] = p0; gp[1] = p1;
    }
}

// ---------------- x (fp32) -> xh (f16) ----------------
__global__ void moe_cvt_x_kernel(const float4* __restrict__ x, f16x4* __restrict__ xh, int n4) {
    int i = blockIdx.x * blockDim.x + threadIdx.x;
    if (i < n4) {
        float4 v = x[i];
        f16x4 h = { (_Float16)v.x, (_Float16)v.y, (_Float16)v.z, (_Float16)v.w };
        xh[i] = h;
    }
}

// ---------------- We [e][i][o] fp32 -> wt [e][o][i] f16 (B^T per expert) ----------------
__global__ void moe_transpose_we_kernel(const float* __restrict__ We, _Float16* __restrict__ wt) {
    __shared__ float t[64][65];
    int e  = blockIdx.z;
    int i0 = blockIdx.x * 64;   // in_f tile
    int o0 = blockIdx.y * 64;   // out_f tile
    const float* src = We + ((size_t)e << 20);
    int oo = threadIdx.x & 63;
    int ib = threadIdx.x >> 6;  // 0..3
#pragma unroll
    for (int r = 0; r < 16; ++r) {
        int i = ib + r * 4;
        t[i][oo] = src[(size_t)(i0 + i) * OUT_F + o0 + oo];
    }
    __syncthreads();
    _Float16* dst = wt + ((size_t)e << 20);
#pragma unroll
    for (int r = 0; r < 16; ++r) {
        int o = ib + r * 4;
        dst[(size_t)(o0 + o) * IN_F + i0 + oo] = (_Float16)t[oo][o];
    }
}

// ---------------- out init: out[n][o] = sum_e g[n][e] * be[e][o] ----------------
__global__ void moe_init_out_kernel(const float* __restrict__ g, const float* __restrict__ be,
                                    float* __restrict__ out) {
    int idx = blockIdx.x * 256 + threadIdx.x;      // M*OUT/4 threads
    int n   = idx >> 8;                            // OUT_F/4 = 256 float4 per row
    int o4  = idx & 255;
    const float4* be4 = (const float4*)be;
    const float* gr = g + (size_t)n * 8;
    float4 a = {0.f, 0.f, 0.f, 0.f};
#pragma unroll
    for (int e = 0; e < 8; ++e) {
        float ge = gr[e];
        float4 b = be4[e * 256 + o4];
        a.x = fmaf(ge, b.x, a.x); a.y = fmaf(ge, b.y, a.y);
        a.z = fmaf(ge, b.z, a.z); a.w = fmaf(ge, b.w, a.w);
    }
    ((float4*)out)[idx] = a;
}

// ---------------- main MFMA GEMM: out += g[:,e] * (xh @ We[e]) ----------------
__device__ __forceinline__ void async16(const void* gp, void* lp) {
    __builtin_amdgcn_global_load_lds((const __attribute__((address_space(1))) void*)gp,
                                     (__attribute__((address_space(3))) void*)lp, 16, 0, 0);
}

__global__ __launch_bounds__(256, 2) void moe_gemm_kernel(
    const _Float16* __restrict__ xh,   // [M][K] f16
    const _Float16* __restrict__ wt,   // [E][N][K] f16  (B^T per expert)
    const float* __restrict__ g,       // [M][E]
    float* __restrict__ out)           // [M][N] fp32, atomic accumulate
{
    __shared__ __align__(16) _Float16 As[128 * 64];
    __shared__ __align__(16) _Float16 Bs[128 * 64];
    __shared__ float gs[128];

    const int tid  = threadIdx.x;
    const int lane = tid & 63;
    const int wave = tid >> 6;
    const int e    = blockIdx.z;
    const size_t m0 = (size_t)blockIdx.y * 128;
    const size_t n0 = (size_t)blockIdx.x * 128;

    if (tid < 128) gs[tid] = g[(m0 + tid) * 8 + e];

    // Staging: linear 16B chunk L = j*256 + tid -> LDS row = L>>3, phys c8 = L&7.
    // XOR swizzle baked into the GLOBAL source: logical k-chunk = phys_c8 ^ (row&7).
    const int rb = tid >> 3;                  // row within 32-row group
    const int c8 = (tid & 7) ^ (rb & 7);      // swizzled logical k-chunk
    const _Float16* pA = xh + (m0 + rb) * (size_t)IN_F + c8 * 8;
    const _Float16* pB = wt + ((size_t)e << 20) + (n0 + rb) * (size_t)IN_F + c8 * 8;
    char* lA = (char*)As + tid * 16;
    char* lB = (char*)Bs + tid * 16;

    // Fragment read addresses (bytes). A[m=lane&15][k=quad*8+j]; phys c8 = c8_logical ^ (row&7)
    const int quad = lane >> 4;
    const int ml   = lane & 15;
    const int wm   = (wave >> 1) * 64;
    const int wn   = (wave & 1) * 64;
    const int raA0 = (wm + ml) * 128 + (((0 * 4 + quad) ^ (lane & 7)) * 16);
    const int raA1 = (wm + ml) * 128 + (((1 * 4 + quad) ^ (lane & 7)) * 16);
    const int raB0 = (wn + ml) * 128 + (((0 * 4 + quad) ^ (lane & 7)) * 16);
    const int raB1 = (wn + ml) * 128 + (((1 * 4 + quad) ^ (lane & 7)) * 16);

    f32x4 acc[4][4] = {};

    for (int kt = 0; kt < IN_F / 64; ++kt) {
        const _Float16* sA = pA + kt * 64;
        const _Float16* sB = pB + kt * 64;
#pragma unroll
        for (int j = 0; j < 4; ++j) {
            async16(sA + j * 32 * IN_F, lA + j * 4096);
            async16(sB + j * 32 * IN_F, lB + j * 4096);
        }
        __syncthreads();   // compiler inserts vmcnt(0) drain for the LDS-bound loads
#pragma unroll
        for (int s = 0; s < 2; ++s) {
            const int rA = s ? raA1 : raA0;
            const int rB = s ? raB1 : raB0;
            f16x8 af[4], bf[4];
#pragma unroll
            for (int t = 0; t < 4; ++t) af[t] = *(const f16x8*)((const char*)As + rA + t * 2048);
#pragma unroll
            for (int t = 0; t < 4; ++t) bf[t] = *(const f16x8*)((const char*)Bs + rB + t * 2048);
#pragma unroll
            for (int i = 0; i < 4; ++i)
#pragma unroll
                for (int jn = 0; jn < 4; ++jn)
                    acc[i][jn] = __builtin_amdgcn_mfma_f32_16x16x32_f16(af[i], bf[jn], acc[i][jn], 0, 0, 0);
        }
        __syncthreads();
    }

    // Epilogue: C/D layout col = lane&15, row = quad*4 + reg. Scale by gate, atomic add.
#pragma unroll
    for (int i = 0; i < 4; ++i) {
        const int rowb = wm + i * 16 + quad * 4;
#pragma unroll
        for (int jn = 0; jn < 4; ++jn) {
            const size_t col = n0 + wn + jn * 16 + ml;
#pragma unroll
            for (int r = 0; r < 4; ++r) {
                float v = acc[i][jn][r] * gs[rowb + r];
                unsafeAtomicAdd(out + (m0 + rowb + r) * (size_t)OUT_F + col, v);
            }
        }
    }
}

extern "C" void kernel_launch(void* const* d_in, const int* in_sizes, int n_in,
                              void* d_out, int out_size, void* d_ws, size_t ws_size,
                              hipStream_t stream) {
    const float* x  = (const float*)d_in[0];
    const float* We = (const float*)d_in[1];
    const float* be = (const float*)d_in[2];
    const float* Wg = (const float*)d_in[3];
    const float* bg = (const float*)d_in[4];
    float* out = (float*)d_out;

    char* ws = (char*)d_ws;
    float*    g  = (float*)ws;                                   // 8192*8*4   = 256 KB
    _Float16* xh = (_Float16*)(ws + (1 << 18));                  // 8192*1024*2 = 16 MB
    _Float16* wt = (_Float16*)(ws + (1 << 18) + (1 << 24));      // 8*1024*1024*2 = 16 MB
    // total ws needed: ~33.8 MB

    moe_gate_kernel<<<M_TOK / 4, 256, 0, stream>>>(x, Wg, bg, g);
    moe_cvt_x_kernel<<<(M_TOK * IN_F / 4) / 256, 256, 0, stream>>>((const float4*)x, (f16x4*)xh,
                                                                   M_TOK * IN_F / 4);
    moe_transpose_we_kernel<<<dim3(IN_F / 64, OUT_F / 64, N_EXP), 256, 0, stream>>>(We, wt);
    moe_init_out_kernel<<<(M_TOK * OUT_F / 4) / 256, 256, 0, stream>>>(g, be, out);
    moe_gemm_kernel<<<dim3(OUT_F / 128, M_TOK / 128, N_EXP), 256, 0, stream>>>(xh, wt, g, out);
}